// Round 1
// baseline (59.632 us; speedup 1.0000x reference)
//
#include <hip/hip_runtime.h>

// Direct-Form-II biquad over [B=64][T=262144], parallelized as a chunked
// affine scan:  v[t+1] = A v[t] + c x[t],  A = [[-a1,1],[-a2,0]],
//               out[t] = b0 x[t] + v0[t].
// Pass1: per-chunk particular end-state (zero init). Pass2: per-batch wave
// scan of carries with M = A^L (device-computed, repeated squaring).
// Pass3: re-run chunks from correct v_init, write outputs.

constexpr int BATCH = 64;
constexpr int T_LEN = 262144;
constexpr int L = 128;            // time-steps per thread-chunk
constexpr int C = T_LEN / L;      // 2048 chunks per batch
constexpr int LOG2C = 11;

#define BIQUAD_STEP(xv)                                            \
    {                                                              \
        float o_  = fmaf((xv), b0, v0);                            \
        float n0_ = fmaf(na1, o_, fmaf((xv), b1, v1));             \
        float n1_ = fmaf(na2, o_, (xv) * b2);                      \
        v0 = n0_; v1 = n1_;                                        \
    }

#define BIQUAD_STEP_OUT(xv, odst)                                  \
    {                                                              \
        float o_  = fmaf((xv), b0, v0);                            \
        float n0_ = fmaf(na1, o_, fmaf((xv), b1, v1));             \
        float n1_ = fmaf(na2, o_, (xv) * b2);                      \
        v0 = n0_; v1 = n1_; (odst) = o_;                           \
    }

__global__ __launch_bounds__(256) void biquad_pass1(
    const float* __restrict__ x, float* __restrict__ carry,
    const float* __restrict__ pb0, const float* __restrict__ pb1,
    const float* __restrict__ pb2, const float* __restrict__ pa1,
    const float* __restrict__ pa2)
{
    const int g = blockIdx.x * 256 + threadIdx.x;   // [0, BATCH*C)
    const int b = g >> LOG2C;
    const int c = g & (C - 1);
    const float b0 = *pb0, b1 = *pb1, b2 = *pb2;
    const float na1 = -*pa1, na2 = -*pa2;

    const float4* xp = reinterpret_cast<const float4*>(
        x + (size_t)b * T_LEN + (size_t)c * L);

    float v0 = 0.f, v1 = 0.f;
#pragma unroll
    for (int i = 0; i < L / 4; ++i) {
        float4 xv = xp[i];
        BIQUAD_STEP(xv.x);
        BIQUAD_STEP(xv.y);
        BIQUAD_STEP(xv.z);
        BIQUAD_STEP(xv.w);
    }
    carry[2 * g]     = v0;
    carry[2 * g + 1] = v1;
}

// One wave (64 lanes) per batch. Each lane owns R = C/64 = 32 consecutive
// carries: serial-compose, Hillis-Steele wave scan (matrix doubles by
// squaring each step -- uniform across lanes), then emit per-chunk v_init.
__global__ __launch_bounds__(64) void biquad_pass2(
    const float* __restrict__ carry, float* __restrict__ vinit,
    const float* __restrict__ pa1, const float* __restrict__ pa2)
{
    const int b = blockIdx.x;      // 64 blocks
    const int lane = threadIdx.x;  // 64 lanes
    const float a1 = *pa1, a2 = *pa2;

    // M = A^L, A = [[-a1, 1], [-a2, 0]];  L = 128 = 2^7 -> 7 squarings
    float m00 = -a1, m01 = 1.f, m10 = -a2, m11 = 0.f;
#pragma unroll
    for (int s = 0; s < 7; ++s) {
        float n00 = fmaf(m00, m00, m01 * m10);
        float n01 = fmaf(m00, m01, m01 * m11);
        float n10 = fmaf(m10, m00, m11 * m10);
        float n11 = fmaf(m10, m01, m11 * m11);
        m00 = n00; m01 = n01; m10 = n10; m11 = n11;
    }

    constexpr int R = C / 64;   // 32 carries per lane
    const float* cb = carry + ((size_t)b * C + (size_t)lane * R) * 2;

    // serial compose this lane's R carries (zero init)
    float p0 = 0.f, p1 = 0.f;
#pragma unroll
    for (int j = 0; j < R; ++j) {
        float q0 = cb[2 * j], q1 = cb[2 * j + 1];
        float n0 = fmaf(m00, p0, fmaf(m01, p1, q0));
        float n1 = fmaf(m10, p0, fmaf(m11, p1, q1));
        p0 = n0; p1 = n1;
    }

    // W = M^R (5 more squarings from M=A^128 -> A^(128*32))
    float w00 = m00, w01 = m01, w10 = m10, w11 = m11;
#pragma unroll
    for (int s = 0; s < 5; ++s) {
        float n00 = fmaf(w00, w00, w01 * w10);
        float n01 = fmaf(w00, w01, w01 * w11);
        float n10 = fmaf(w10, w00, w11 * w10);
        float n11 = fmaf(w10, w01, w11 * w11);
        w00 = n00; w01 = n01; w10 = n10; w11 = n11;
    }

    // Hillis-Steele inclusive scan across 64 lanes; W squares each step
    for (int d = 1; d < 64; d <<= 1) {
        float o0 = __shfl_up(p0, d);
        float o1 = __shfl_up(p1, d);
        if (lane >= d) {
            p0 = fmaf(w00, o0, fmaf(w01, o1, p0));
            p1 = fmaf(w10, o0, fmaf(w11, o1, p1));
        }
        float n00 = fmaf(w00, w00, w01 * w10);
        float n01 = fmaf(w00, w01, w01 * w11);
        float n10 = fmaf(w10, w00, w11 * w10);
        float n11 = fmaf(w10, w01, w11 * w11);
        w00 = n00; w01 = n01; w10 = n10; w11 = n11;
    }

    // exclusive prefix = inclusive of lane-1; lane 0 starts at v=0
    float e0 = __shfl_up(p0, 1);
    float e1 = __shfl_up(p1, 1);
    if (lane == 0) { e0 = 0.f; e1 = 0.f; }

    // emit per-chunk initial states for this lane's R chunks
    float v0 = e0, v1 = e1;
    float* vb = vinit + ((size_t)b * C + (size_t)lane * R) * 2;
#pragma unroll
    for (int j = 0; j < R; ++j) {
        vb[2 * j]     = v0;
        vb[2 * j + 1] = v1;
        float q0 = cb[2 * j], q1 = cb[2 * j + 1];
        float n0 = fmaf(m00, v0, fmaf(m01, v1, q0));
        float n1 = fmaf(m10, v0, fmaf(m11, v1, q1));
        v0 = n0; v1 = n1;
    }
}

__global__ __launch_bounds__(256) void biquad_pass3(
    const float* __restrict__ x, const float* __restrict__ vinit,
    float* __restrict__ out,
    const float* __restrict__ pb0, const float* __restrict__ pb1,
    const float* __restrict__ pb2, const float* __restrict__ pa1,
    const float* __restrict__ pa2)
{
    const int g = blockIdx.x * 256 + threadIdx.x;
    const int b = g >> LOG2C;
    const int c = g & (C - 1);
    const float b0 = *pb0, b1 = *pb1, b2 = *pb2;
    const float na1 = -*pa1, na2 = -*pa2;

    const size_t base = (size_t)b * T_LEN + (size_t)c * L;
    const float4* xp = reinterpret_cast<const float4*>(x + base);
    float4* op       = reinterpret_cast<float4*>(out + base);

    float v0 = vinit[2 * g];
    float v1 = vinit[2 * g + 1];

#pragma unroll
    for (int i = 0; i < L / 4; ++i) {
        float4 xv = xp[i];
        float4 ov;
        BIQUAD_STEP_OUT(xv.x, ov.x);
        BIQUAD_STEP_OUT(xv.y, ov.y);
        BIQUAD_STEP_OUT(xv.z, ov.z);
        BIQUAD_STEP_OUT(xv.w, ov.w);
        op[i] = ov;
    }
}

extern "C" void kernel_launch(void* const* d_in, const int* in_sizes, int n_in,
                              void* d_out, int out_size, void* d_ws, size_t ws_size,
                              hipStream_t stream) {
    const float* x   = (const float*)d_in[0];
    const float* pb0 = (const float*)d_in[1];
    const float* pb1 = (const float*)d_in[2];
    const float* pb2 = (const float*)d_in[3];
    const float* pa1 = (const float*)d_in[4];
    const float* pa2 = (const float*)d_in[5];
    float* out = (float*)d_out;

    // workspace layout: carries [B*C*2] f32, then vinit [B*C*2] f32 (1 MB each)
    float* carry = (float*)d_ws;
    float* vinit = carry + (size_t)BATCH * C * 2;

    const int nthreads = BATCH * C;            // 131072
    biquad_pass1<<<nthreads / 256, 256, 0, stream>>>(x, carry, pb0, pb1, pb2, pa1, pa2);
    biquad_pass2<<<BATCH, 64, 0, stream>>>(carry, vinit, pa1, pa2);
    biquad_pass3<<<nthreads / 256, 256, 0, stream>>>(x, vinit, out, pb0, pb1, pb2, pa1, pa2);
}

// Round 2
// 47.338 us; speedup vs baseline: 1.2597x; 1.2597x over previous
//
#include <hip/hip_runtime.h>

// Direct-Form-II biquad over [B=64][T=262144] as a chunked affine scan.
//   v[t+1] = A v[t] + c x[t],  A = [[-a1,1],[-a2,0]],  out[t] = b0 x[t] + v0[t]
// L=32 samples/chunk. Pass1: per-chunk end-state (zero init), LDS-staged
// coalesced loads. Pass2: per-batch 256-thread block scan of 8192 carries
// (uniform matrix powers -> Hillis-Steele with squaring), in-place carry->vinit.
// Pass3: re-run chunks from vinit, outputs staged through LDS for coalesced
// 1-KB wave stores.

constexpr int BATCH = 64;
constexpr int T_LEN = 262144;
constexpr int L     = 32;            // samples per chunk
constexpr int CPB   = T_LEN / L;     // 8192 chunks per batch
constexpr int G     = BATCH * CPB;   // 524288 chunks total
constexpr int TPB   = 256;           // threads per block (pass1/pass3)
constexpr int WPB   = TPB / 64;      // 4 waves per block
constexpr int ROWS  = 64;            // chunks per wave region
constexpr int PAD   = 33;            // padded LDS row (floats) -> bank (lane+t)%32
constexpr int ITERS = ROWS * L / (64 * 4);   // 8 coalesced float4 iters per region

__global__ __launch_bounds__(TPB) void biquad_pass1(
    const float* __restrict__ x, float* __restrict__ carry,
    const float* __restrict__ pb0, const float* __restrict__ pb1,
    const float* __restrict__ pb2, const float* __restrict__ pa1,
    const float* __restrict__ pa2)
{
    __shared__ float lds[WPB][ROWS][PAD];
    const int tid  = threadIdx.x;
    const int w    = tid >> 6;
    const int lane = tid & 63;
    const int c0   = blockIdx.x * TPB + w * 64;   // wave's first chunk (global)
    const float b0 = *pb0, b1 = *pb1, b2 = *pb2;
    const float na1 = -*pa1, na2 = -*pa2;

    // stage 8 KB region: fully coalesced (1 KB per wave instruction)
    const float4* src = reinterpret_cast<const float4*>(x + (size_t)c0 * L);
#pragma unroll
    for (int it = 0; it < ITERS; ++it) {
        float4 v = src[it * 64 + lane];
        int e = (it * 64 + lane) * 4;        // element within region
        int c = e >> 5, t = e & 31;
        lds[w][c][t]     = v.x;
        lds[w][c][t + 1] = v.y;
        lds[w][c][t + 2] = v.z;
        lds[w][c][t + 3] = v.w;
    }
    __syncthreads();

    float v0 = 0.f, v1 = 0.f;
#pragma unroll
    for (int t = 0; t < L; ++t) {
        float xv = lds[w][lane][t];
        float o  = fmaf(xv, b0, v0);
        float n0 = fmaf(na1, o, fmaf(xv, b1, v1));
        v1 = fmaf(na2, o, xv * b2);
        v0 = n0;
    }
    reinterpret_cast<float2*>(carry)[c0 + lane] = make_float2(v0, v1);
}

// One 256-thread block per batch scans its 8192 carries. All segment
// transforms are powers of A (uniform across lanes), so Hillis-Steele just
// squares the matrix each round. In-place: carry slots become vinit.
__global__ __launch_bounds__(256) void biquad_pass2(
    float* __restrict__ buf,
    const float* __restrict__ pa1, const float* __restrict__ pa2)
{
    __shared__ float sp0[256], sp1[256];
    const int b = blockIdx.x, tid = threadIdx.x, lane = tid & 63;
    const float a1 = *pa1, a2 = *pa2;

    // M = A^L = A^32 (5 squarings from A)
    float m00 = -a1, m01 = 1.f, m10 = -a2, m11 = 0.f;
#pragma unroll
    for (int s = 0; s < 5; ++s) {
        float n00 = fmaf(m00, m00, m01 * m10);
        float n01 = fmaf(m00, m01, m01 * m11);
        float n10 = fmaf(m10, m00, m11 * m10);
        float n11 = fmaf(m10, m01, m11 * m11);
        m00 = n00; m01 = n01; m10 = n10; m11 = n11;
    }

    constexpr int R = CPB / 256;   // 32 chunks per thread
    float* cb = buf + ((size_t)b * CPB + (size_t)tid * R) * 2;

    // serial compose this thread's R carries (zero init)
    float p0 = 0.f, p1 = 0.f;
#pragma unroll
    for (int j = 0; j < R; ++j) {
        float q0 = cb[2 * j], q1 = cb[2 * j + 1];
        float n0 = fmaf(m00, p0, fmaf(m01, p1, q0));
        float n1 = fmaf(m10, p0, fmaf(m11, p1, q1));
        p0 = n0; p1 = n1;
    }

    // W = M^R (5 more squarings)
    float w00 = m00, w01 = m01, w10 = m10, w11 = m11;
#pragma unroll
    for (int s = 0; s < 5; ++s) {
        float n00 = fmaf(w00, w00, w01 * w10);
        float n01 = fmaf(w00, w01, w01 * w11);
        float n10 = fmaf(w10, w00, w11 * w10);
        float n11 = fmaf(w10, w01, w11 * w11);
        w00 = n00; w01 = n01; w10 = n10; w11 = n11;
    }

    // in-wave scan (d = 1..32), W squares each round
    for (int d = 1; d < 64; d <<= 1) {
        float o0 = __shfl_up(p0, d);
        float o1 = __shfl_up(p1, d);
        if (lane >= d) {
            p0 = fmaf(w00, o0, fmaf(w01, o1, p0));
            p1 = fmaf(w10, o0, fmaf(w11, o1, p1));
        }
        float n00 = fmaf(w00, w00, w01 * w10);
        float n01 = fmaf(w00, w01, w01 * w11);
        float n10 = fmaf(w10, w00, w11 * w10);
        float n11 = fmaf(w10, w01, w11 * w11);
        w00 = n00; w01 = n01; w10 = n10; w11 = n11;
    }

    // cross-wave rounds (d = 64, 128) via LDS
    for (int d = 64; d < 256; d <<= 1) {
        sp0[tid] = p0; sp1[tid] = p1;
        __syncthreads();
        float o0 = 0.f, o1 = 0.f;
        const bool has = (tid >= d);
        if (has) { o0 = sp0[tid - d]; o1 = sp1[tid - d]; }
        __syncthreads();
        if (has) {
            p0 = fmaf(w00, o0, fmaf(w01, o1, p0));
            p1 = fmaf(w10, o0, fmaf(w11, o1, p1));
        }
        float n00 = fmaf(w00, w00, w01 * w10);
        float n01 = fmaf(w00, w01, w01 * w11);
        float n10 = fmaf(w10, w00, w11 * w10);
        float n11 = fmaf(w10, w01, w11 * w11);
        w00 = n00; w01 = n01; w10 = n10; w11 = n11;
    }

    // exclusive prefix across the block
    sp0[tid] = p0; sp1[tid] = p1;
    __syncthreads();
    float e0 = 0.f, e1 = 0.f;
    if (tid > 0) { e0 = sp0[tid - 1]; e1 = sp1[tid - 1]; }

    // emit per-chunk initial states, in-place over the carries
    float v0 = e0, v1 = e1;
#pragma unroll
    for (int j = 0; j < R; ++j) {
        float q0 = cb[2 * j], q1 = cb[2 * j + 1];
        cb[2 * j]     = v0;
        cb[2 * j + 1] = v1;
        float n0 = fmaf(m00, v0, fmaf(m01, v1, q0));
        float n1 = fmaf(m10, v0, fmaf(m11, v1, q1));
        v0 = n0; v1 = n1;
    }
}

__global__ __launch_bounds__(TPB) void biquad_pass3(
    const float* __restrict__ x, const float* __restrict__ vinit,
    float* __restrict__ out,
    const float* __restrict__ pb0, const float* __restrict__ pb1,
    const float* __restrict__ pb2, const float* __restrict__ pa1,
    const float* __restrict__ pa2)
{
    __shared__ float lds[WPB][ROWS][PAD];
    const int tid  = threadIdx.x;
    const int w    = tid >> 6;
    const int lane = tid & 63;
    const int c0   = blockIdx.x * TPB + w * 64;
    const float b0 = *pb0, b1 = *pb1, b2 = *pb2;
    const float na1 = -*pa1, na2 = -*pa2;

    const float4* src = reinterpret_cast<const float4*>(x + (size_t)c0 * L);
#pragma unroll
    for (int it = 0; it < ITERS; ++it) {
        float4 v = src[it * 64 + lane];
        int e = (it * 64 + lane) * 4;
        int c = e >> 5, t = e & 31;
        lds[w][c][t]     = v.x;
        lds[w][c][t + 1] = v.y;
        lds[w][c][t + 2] = v.z;
        lds[w][c][t + 3] = v.w;
    }
    __syncthreads();

    float2 vi = reinterpret_cast<const float2*>(vinit)[c0 + lane];
    float v0 = vi.x, v1 = vi.y;
#pragma unroll
    for (int t = 0; t < L; ++t) {
        float xv = lds[w][lane][t];
        float o  = fmaf(xv, b0, v0);
        float n0 = fmaf(na1, o, fmaf(xv, b1, v1));
        v1 = fmaf(na2, o, xv * b2);
        v0 = n0;
        lds[w][lane][t] = o;     // in-place: tile becomes the output tile
    }
    __syncthreads();

    float4* dst = reinterpret_cast<float4*>(out + (size_t)c0 * L);
#pragma unroll
    for (int it = 0; it < ITERS; ++it) {
        int e = (it * 64 + lane) * 4;
        int c = e >> 5, t = e & 31;
        float4 v;
        v.x = lds[w][c][t];
        v.y = lds[w][c][t + 1];
        v.z = lds[w][c][t + 2];
        v.w = lds[w][c][t + 3];
        dst[it * 64 + lane] = v;
    }
}

extern "C" void kernel_launch(void* const* d_in, const int* in_sizes, int n_in,
                              void* d_out, int out_size, void* d_ws, size_t ws_size,
                              hipStream_t stream) {
    const float* x   = (const float*)d_in[0];
    const float* pb0 = (const float*)d_in[1];
    const float* pb1 = (const float*)d_in[2];
    const float* pb2 = (const float*)d_in[3];
    const float* pa1 = (const float*)d_in[4];
    const float* pa2 = (const float*)d_in[5];
    float* out = (float*)d_out;

    // single 4 MB workspace buffer: carries, overwritten in-place with vinit
    float* buf = (float*)d_ws;

    biquad_pass1<<<G / TPB, TPB, 0, stream>>>(x, buf, pb0, pb1, pb2, pa1, pa2);
    biquad_pass2<<<BATCH, 256, 0, stream>>>(buf, pa1, pa2);
    biquad_pass3<<<G / TPB, TPB, 0, stream>>>(x, buf, out, pb0, pb1, pb2, pa1, pa2);
}